// Round 5
// baseline (235.689 us; speedup 1.0000x reference)
//
#include <hip/hip_runtime.h>
#include <hip/hip_bf16.h>

using bf16 = __hip_bfloat16;
typedef __attribute__((ext_vector_type(8))) __bf16 bf16x8;
typedef __attribute__((ext_vector_type(4))) float f32x4;

#define B_   4
#define T_   2048
#define D_   1024
#define H_   16
#define HD_  64
#define BH_  (B_ * H_)
#define BT_  (B_ * T_)

// async global->LDS DMA, 16B per lane; LDS dest is wave-uniform base + lane*16
__device__ __forceinline__ void gld_lds16(const void* g, void* l) {
    __builtin_amdgcn_global_load_lds(
        (const __attribute__((address_space(1))) unsigned int*)g,
        (__attribute__((address_space(3))) unsigned int*)l,
        16, 0, 0);
}

// ---------------------------------------------------------------- cast fp32 -> bf16
__global__ void cast_kernel(const float* __restrict__ in, bf16* __restrict__ out, int n4) {
    int i = blockIdx.x * 256 + threadIdx.x;
    if (i >= n4) return;
    float4 v = reinterpret_cast<const float4*>(in)[i];
    union { bf16 h[4]; uint2 u; } tmp;
    tmp.h[0] = __float2bfloat16(v.x);
    tmp.h[1] = __float2bfloat16(v.y);
    tmp.h[2] = __float2bfloat16(v.z);
    tmp.h[3] = __float2bfloat16(v.w);
    reinterpret_cast<uint2*>(out)[i] = tmp.u;
}

// ---------------------------------------------------------------- W[K][N] fp32 -> Wt[N][K] bf16
__global__ void transpose_cast(const float* __restrict__ W, bf16* __restrict__ Wt,
                               int K, int N) {
    __shared__ float tile[32][33];
    int nb = blockIdx.x * 32, kb = blockIdx.y * 32;
    int tx = threadIdx.x, ty = threadIdx.y;   // 32 x 8
    #pragma unroll
    for (int i = 0; i < 32; i += 8)
        tile[ty + i][tx] = W[(size_t)(kb + ty + i) * N + nb + tx];
    __syncthreads();
    #pragma unroll
    for (int i = 0; i < 32; i += 8)
        Wt[(size_t)(nb + ty + i) * K + kb + tx] = __float2bfloat16(tile[tx][ty + i]);
}

// ---------------------------------------------------------------- 256x256 8-phase GEMM
// C = A @ Bt^T (+bias). A: [M][1024] bf16, Bt: [N][1024] bf16. K fixed = 1024.
// 8 waves (2M x 4N), per-wave 128x64 C. BK=32, ring-4 LDS slots (128 KiB dynamic).
// Stage tile t+3 while computing tile t; vmcnt(8) per tile (counted, never 0 mid-loop).
// LDS swizzle: 16B-slot ^= (row>>1)&3  (reads: colA const-folded; DMA: lane permute).
// MODE 0: QKV scatter epilogue (Q*0.125, K, V^T). MODE 1: fp32 out + bias.
template <int MODE>
__global__ __launch_bounds__(512, 2)
void gemm256(const bf16* __restrict__ A, const bf16* __restrict__ Bt,
             const float* __restrict__ bias,
             bf16* __restrict__ Qo, bf16* __restrict__ Ko, bf16* __restrict__ Vo,
             float* __restrict__ Fo) {
    extern __shared__ char smem[];

    // bijective XCD swizzle (gridDim.x % 8 == 0), m-major within chunk
    const int cpx = gridDim.x >> 3;
    const int wk  = (blockIdx.x & 7) * cpx + (blockIdx.x >> 3);
    const int bm = (wk & 31) * 256;            // M = 8192 -> 32 m-tiles
    const int bn = (wk >> 5) * 256;

    const int tid  = threadIdx.x;
    const int wid  = tid >> 6;
    const int lane = tid & 63;
    const int ln_g = lane >> 4;     // 0..3
    const int ln_c = lane & 15;     // 0..15
    const int wr = (wid >> 2) * 128;
    const int wc = (wid & 3) * 64;

    // --- staging lane mapping (inverse swizzle on global source)
    const int srl = lane >> 2;                        // row in 16-row stripe
    const int sch = (lane & 3) ^ ((lane >> 3) & 3);   // pre-swizzled 16B chunk
    const size_t arow = (size_t)(bm + wid * 16 + srl) * 1024 + sch * 8;
    const size_t brow = (size_t)(bn + wid * 16 + srl) * 1024 + sch * 8;
    const int ldsw = wid * 1024;

    // --- read bases (swizzle folds to a constant column offset per thread)
    const int colA = (ln_g * 16) ^ (((ln_c >> 1) & 3) << 4);
    const char* aB = smem + (wr + ln_c) * 64 + colA;
    const char* bB = smem + 16384 + (wc + ln_c) * 64 + colA;

    f32x4 acc[8][4] = {};

#define STAGE_A(U_, S_) { \
    gld_lds16(A + arow + (size_t)(U_) * 32,              smem + (S_) * 32768 + ldsw); \
    gld_lds16(A + arow + 131072 + (size_t)(U_) * 32,     smem + (S_) * 32768 + 8192 + ldsw); }
#define STAGE_B(U_, S_) { \
    gld_lds16(Bt + brow + (size_t)(U_) * 32,             smem + (S_) * 32768 + 16384 + ldsw); \
    gld_lds16(Bt + brow + 131072 + (size_t)(U_) * 32,    smem + (S_) * 32768 + 24576 + ldsw); }
#define RDA(S_, MI_) (*(const bf16x8*)(aB + (S_) * 32768 + (MI_) * 1024))
#define RDB(S_, NI_) (*(const bf16x8*)(bB + (S_) * 32768 + (NI_) * 1024))
#define BAR()  __builtin_amdgcn_s_barrier()
#define SB()   __builtin_amdgcn_sched_barrier(0)
#define VM8 asm volatile("s_waitcnt vmcnt(8)")
#define VM4 asm volatile("s_waitcnt vmcnt(4)")
#define VM0 asm volatile("s_waitcnt vmcnt(0)")
#define VMN ((void)0)

#define KTILE(T_, S_, DOSTG_, VM_)                                                   \
  {                                                                                  \
    bf16x8 a0_ = RDA(S_, 0), a1_ = RDA(S_, 1), a2_ = RDA(S_, 2), a3_ = RDA(S_, 3);   \
    bf16x8 b0_ = RDB(S_, 0), b1_ = RDB(S_, 1), b2_ = RDB(S_, 2), b3_ = RDB(S_, 3);   \
    if (DOSTG_) STAGE_A((T_) + 3, ((T_) + 3) & 3);                                   \
    BAR(); SB();                                                                     \
    __builtin_amdgcn_s_setprio(1);                                                   \
    acc[0][0] = __builtin_amdgcn_mfma_f32_16x16x32_bf16(a0_, b0_, acc[0][0], 0,0,0); \
    acc[0][1] = __builtin_amdgcn_mfma_f32_16x16x32_bf16(a0_, b1_, acc[0][1], 0,0,0); \
    acc[0][2] = __builtin_amdgcn_mfma_f32_16x16x32_bf16(a0_, b2_, acc[0][2], 0,0,0); \
    acc[0][3] = __builtin_amdgcn_mfma_f32_16x16x32_bf16(a0_, b3_, acc[0][3], 0,0,0); \
    acc[1][0] = __builtin_amdgcn_mfma_f32_16x16x32_bf16(a1_, b0_, acc[1][0], 0,0,0); \
    acc[1][1] = __builtin_amdgcn_mfma_f32_16x16x32_bf16(a1_, b1_, acc[1][1], 0,0,0); \
    acc[1][2] = __builtin_amdgcn_mfma_f32_16x16x32_bf16(a1_, b2_, acc[1][2], 0,0,0); \
    acc[1][3] = __builtin_amdgcn_mfma_f32_16x16x32_bf16(a1_, b3_, acc[1][3], 0,0,0); \
    acc[2][0] = __builtin_amdgcn_mfma_f32_16x16x32_bf16(a2_, b0_, acc[2][0], 0,0,0); \
    acc[2][1] = __builtin_amdgcn_mfma_f32_16x16x32_bf16(a2_, b1_, acc[2][1], 0,0,0); \
    acc[2][2] = __builtin_amdgcn_mfma_f32_16x16x32_bf16(a2_, b2_, acc[2][2], 0,0,0); \
    acc[2][3] = __builtin_amdgcn_mfma_f32_16x16x32_bf16(a2_, b3_, acc[2][3], 0,0,0); \
    acc[3][0] = __builtin_amdgcn_mfma_f32_16x16x32_bf16(a3_, b0_, acc[3][0], 0,0,0); \
    acc[3][1] = __builtin_amdgcn_mfma_f32_16x16x32_bf16(a3_, b1_, acc[3][1], 0,0,0); \
    acc[3][2] = __builtin_amdgcn_mfma_f32_16x16x32_bf16(a3_, b2_, acc[3][2], 0,0,0); \
    acc[3][3] = __builtin_amdgcn_mfma_f32_16x16x32_bf16(a3_, b3_, acc[3][3], 0,0,0); \
    __builtin_amdgcn_s_setprio(0);                                                   \
    SB(); BAR();                                                                     \
    a0_ = RDA(S_, 4); a1_ = RDA(S_, 5); a2_ = RDA(S_, 6); a3_ = RDA(S_, 7);          \
    if (DOSTG_) STAGE_B((T_) + 3, ((T_) + 3) & 3);                                   \
    BAR(); SB();                                                                     \
    __builtin_amdgcn_s_setprio(1);                                                   \
    acc[4][0] = __builtin_amdgcn_mfma_f32_16x16x32_bf16(a0_, b0_, acc[4][0], 0,0,0); \
    acc[4][1] = __builtin_amdgcn_mfma_f32_16x16x32_bf16(a0_, b1_, acc[4][1], 0,0,0); \
    acc[4][2] = __builtin_amdgcn_mfma_f32_16x16x32_bf16(a0_, b2_, acc[4][2], 0,0,0); \
    acc[4][3] = __builtin_amdgcn_mfma_f32_16x16x32_bf16(a0_, b3_, acc[4][3], 0,0,0); \
    acc[5][0] = __builtin_amdgcn_mfma_f32_16x16x32_bf16(a1_, b0_, acc[5][0], 0,0,0); \
    acc[5][1] = __builtin_amdgcn_mfma_f32_16x16x32_bf16(a1_, b1_, acc[5][1], 0,0,0); \
    acc[5][2] = __builtin_amdgcn_mfma_f32_16x16x32_bf16(a1_, b2_, acc[5][2], 0,0,0); \
    acc[5][3] = __builtin_amdgcn_mfma_f32_16x16x32_bf16(a1_, b3_, acc[5][3], 0,0,0); \
    acc[6][0] = __builtin_amdgcn_mfma_f32_16x16x32_bf16(a2_, b0_, acc[6][0], 0,0,0); \
    acc[6][1] = __builtin_amdgcn_mfma_f32_16x16x32_bf16(a2_, b1_, acc[6][1], 0,0,0); \
    acc[6][2] = __builtin_amdgcn_mfma_f32_16x16x32_bf16(a2_, b2_, acc[6][2], 0,0,0); \
    acc[6][3] = __builtin_amdgcn_mfma_f32_16x16x32_bf16(a2_, b3_, acc[6][3], 0,0,0); \
    acc[7][0] = __builtin_amdgcn_mfma_f32_16x16x32_bf16(a3_, b0_, acc[7][0], 0,0,0); \
    acc[7][1] = __builtin_amdgcn_mfma_f32_16x16x32_bf16(a3_, b1_, acc[7][1], 0,0,0); \
    acc[7][2] = __builtin_amdgcn_mfma_f32_16x16x32_bf16(a3_, b2_, acc[7][2], 0,0,0); \
    acc[7][3] = __builtin_amdgcn_mfma_f32_16x16x32_bf16(a3_, b3_, acc[7][3], 0,0,0); \
    __builtin_amdgcn_s_setprio(0);                                                   \
    SB();                                                                            \
    VM_;                                                                             \
    BAR();                                                                           \
  }

    // prologue: stage tiles 0,1,2; wait tile 0 landed (8 newer calls allowed)
    STAGE_A(0, 0); STAGE_B(0, 0);
    STAGE_A(1, 1); STAGE_B(1, 1);
    STAGE_A(2, 2); STAGE_B(2, 2);
    VM8;
    BAR();

    #pragma unroll 1
    for (int i = 0; i < 7; ++i) {
        const int t0 = i * 4;
        KTILE(t0 + 0, 0, 1, VM8);
        KTILE(t0 + 1, 1, 1, VM8);
        KTILE(t0 + 2, 2, 1, VM8);
        KTILE(t0 + 3, 3, 1, VM8);
    }
    KTILE(28, 0, 1, VM8);
    KTILE(29, 1, 0, VM4);
    KTILE(30, 2, 0, VM0);
    KTILE(31, 3, 0, VMN);

#undef KTILE
#undef STAGE_A
#undef STAGE_B
#undef RDA
#undef RDB

    // epilogue
    #pragma unroll
    for (int m = 0; m < 8; ++m) {
        #pragma unroll
        for (int n = 0; n < 4; ++n) {
            const int col = bn + wc + n * 16 + ln_c;
            const float bcol = bias[col];
            #pragma unroll
            for (int j = 0; j < 4; ++j) {
                const int row = bm + wr + m * 16 + ln_g * 4 + j;
                float v = acc[m][n][j] + bcol;
                if (MODE == 0) {
                    const int part = col >> 10;       // 0=q 1=k 2=v
                    const int cc = col & 1023;
                    const int h = cc >> 6, d = cc & 63;
                    const int b = row >> 11, t = row & 2047;
                    const int bh = b * H_ + h;
                    if (part == 0)
                        Qo[((size_t)bh * T_ + t) * HD_ + d] = __float2bfloat16(v * 0.125f);
                    else if (part == 1)
                        Ko[((size_t)bh * T_ + t) * HD_ + d] = __float2bfloat16(v);
                    else
                        Vo[((size_t)bh * HD_ + d) * T_ + t] = __float2bfloat16(v);
                } else {
                    Fo[(size_t)row * D_ + col] = v;
                }
            }
        }
    }
}

// ---------------------------------------------------------------- causal flash attention v2
// Swapped-operand: S^T = mfma(K, Q) so q = lane&15 (running m/l are lane-scalars);
// O^T = mfma(V^T, P^T) so the alpha rescale is also lane-local.
// Q,K: [bh][t][64] bf16 (Q pre-scaled by 1/8). Vt: [bh][64][t] bf16.
// Grid: (BH, 16 pairs). Block processes q-tiles {p, 31-p}: exactly 33 kv-iters each.
__global__ __launch_bounds__(256)
void attn_kernel(const bf16* __restrict__ Q, const bf16* __restrict__ K,
                 const bf16* __restrict__ Vt, bf16* __restrict__ ctx) {
    const int bh = blockIdx.x;       // 0..63
    const int pr = blockIdx.y;       // 0..15
    const int tid  = threadIdx.x;
    const int wave = tid >> 6;
    const int lane = tid & 63;
    const int ln_g = lane >> 4;      // 0..3
    const int ln_c = lane & 15;      // 0..15

    const bf16* Qp = Q  + (size_t)bh * T_ * HD_;
    const bf16* Kp = K  + (size_t)bh * T_ * HD_;
    const bf16* Vp = Vt + (size_t)bh * HD_ * T_;

    __shared__ bf16 Ks[64][72];
    __shared__ bf16 Vs[64][72];
    __shared__ bf16 Ps[4][16][72];

    const int srow = tid >> 3;       // 0..31
    const int sc8  = (tid & 7) * 8;  // 0..56

    const int b = bh >> 4, h = bh & 15;

    #pragma unroll
    for (int s = 0; s < 2; ++s) {
        const int qt = (s == 0) ? pr : (31 - pr);
        const int qbase = qt * 64;
        const int qglob = qbase + wave * 16 + ln_c;    // this lane's q row

        const bf16x8 qf0 = *reinterpret_cast<const bf16x8*>(&Qp[(size_t)qglob * HD_ + ln_g * 8]);
        const bf16x8 qf1 = *reinterpret_cast<const bf16x8*>(&Qp[(size_t)qglob * HD_ + 32 + ln_g * 8]);

        f32x4 o[4] = {};
        float m = -INFINITY, l = 0.f;

        const int nk = qt + 1;          // 64-wide kv tiles

        int4 kr0, kr1, vr0, vr1;
        {
            kr0 = *reinterpret_cast<const int4*>(&Kp[(size_t)srow * HD_ + sc8]);
            kr1 = *reinterpret_cast<const int4*>(&Kp[(size_t)(srow + 32) * HD_ + sc8]);
            vr0 = *reinterpret_cast<const int4*>(&Vp[(size_t)srow * T_ + sc8]);
            vr1 = *reinterpret_cast<const int4*>(&Vp[(size_t)(srow + 32) * T_ + sc8]);
        }
        __syncthreads();
        *reinterpret_cast<int4*>(&Ks[srow][sc8])      = kr0;
        *reinterpret_cast<int4*>(&Ks[srow + 32][sc8]) = kr1;
        *reinterpret_cast<int4*>(&Vs[srow][sc8])      = vr0;
        *reinterpret_cast<int4*>(&Vs[srow + 32][sc8]) = vr1;
        __syncthreads();

        for (int it = 0; it < nk; ++it) {
            const int kb = it * 64;
            const bool notlast = (it + 1 < nk);
            if (notlast) {
                const int kn = kb + 64;
                kr0 = *reinterpret_cast<const int4*>(&Kp[(size_t)(kn + srow) * HD_ + sc8]);
                kr1 = *reinterpret_cast<const int4*>(&Kp[(size_t)(kn + srow + 32) * HD_ + sc8]);
                vr0 = *reinterpret_cast<const int4*>(&Vp[(size_t)srow * T_ + kn + sc8]);
                vr1 = *reinterpret_cast<const int4*>(&Vp[(size_t)(srow + 32) * T_ + kn + sc8]);
            }

            f32x4 st[4];
            #pragma unroll
            for (int kk = 0; kk < 4; ++kk) {
                bf16x8 kfa = *reinterpret_cast<const bf16x8*>(&Ks[kk * 16 + ln_c][ln_g * 8]);
                bf16x8 kfb = *reinterpret_cast<const bf16x8*>(&Ks[kk * 16 + ln_c][32 + ln_g * 8]);
                f32x4 z = {0.f, 0.f, 0.f, 0.f};
                z = __builtin_amdgcn_mfma_f32_16x16x32_bf16(kfa, qf0, z, 0, 0, 0);
                z = __builtin_amdgcn_mfma_f32_16x16x32_bf16(kfb, qf1, z, 0, 0, 0);
                st[kk] = z;
            }

            if (!notlast) {
                #pragma unroll
                for (int kk = 0; kk < 4; ++kk)
                    #pragma unroll
                    for (int j = 0; j < 4; ++j)
                        if (kb + kk * 16 + ln_g * 4 + j > qglob) st[kk][j] = -INFINITY;
            }

            float mx = -INFINITY;
            #pragma unroll
            for (int kk = 0; kk < 4; ++kk)
                #pragma unroll
                for (int j = 0; j < 4; ++j)
                    mx = fmaxf(mx, st[kk][j]);
            mx = fmaxf(mx, __shfl_xor(mx, 16));
            mx = fmaxf(mx, __shfl_xor(mx, 32));
            const float mnew = fmaxf(m, mx);
            const float alpha = __expf(m - mnew);
            float rs = 0.f;
            #pragma unroll
            for (int kk = 0; kk < 4; ++kk) {
                union { bf16 hh[4]; uint2 u; } pk;
                #pragma unroll
                for (int j = 0; j < 4; ++j) {
                    float p = __expf(st[kk][j] - mnew);
                    rs += p;
                    pk.hh[j] = __float2bfloat16(p);
                }
                *reinterpret_cast<uint2*>(&Ps[wave][ln_c][kk * 16 + ln_g * 4]) = pk.u;
            }
            rs += __shfl_xor(rs, 16);
            rs += __shfl_xor(rs, 32);
            l = l * alpha + rs;
            m = mnew;
            #pragma unroll
            for (int dt = 0; dt < 4; ++dt)
                #pragma unroll
                for (int j = 0; j < 4; ++j)
                    o[dt][j] *= alpha;

            const bf16x8 pf0 = *reinterpret_cast<const bf16x8*>(&Ps[wave][ln_c][ln_g * 8]);
            const bf16x8 pf1 = *reinterpret_cast<const bf16x8*>(&Ps[wave][ln_c][32 + ln_g * 8]);
            #pragma unroll
            for (int dt = 0; dt < 4; ++dt) {
                bf16x8 vfa = *reinterpret_cast<const bf16x8*>(&Vs[dt * 16 + ln_c][ln_g * 8]);
                bf16x8 vfb = *reinterpret_cast<const bf16x8*>(&Vs[dt * 16 + ln_c][32 + ln_g * 8]);
                o[dt] = __builtin_amdgcn_mfma_f32_16x16x32_bf16(vfa, pf0, o[dt], 0, 0, 0);
                o[dt] = __builtin_amdgcn_mfma_f32_16x16x32_bf16(vfb, pf1, o[dt], 0, 0, 0);
            }

            if (notlast) {
                __syncthreads();
                *reinterpret_cast<int4*>(&Ks[srow][sc8])      = kr0;
                *reinterpret_cast<int4*>(&Ks[srow + 32][sc8]) = kr1;
                *reinterpret_cast<int4*>(&Vs[srow][sc8])      = vr0;
                *reinterpret_cast<int4*>(&Vs[srow + 32][sc8]) = vr1;
                __syncthreads();
            }
        }

        const float inv = 1.0f / l;
        bf16* dst = ctx + ((size_t)(b * T_ + qglob)) * D_ + h * HD_;
        #pragma unroll
        for (int dt = 0; dt < 4; ++dt) {
            union { bf16 hh[4]; uint2 u; } ok;
            #pragma unroll
            for (int j = 0; j < 4; ++j)
                ok.hh[j] = __float2bfloat16(o[dt][j] * inv);
            *reinterpret_cast<uint2*>(&dst[dt * 16 + ln_g * 4]) = ok.u;
        }
    }
}

// ---------------------------------------------------------------- launch
extern "C" void kernel_launch(void* const* d_in, const int* in_sizes, int n_in,
                              void* d_out, int out_size, void* d_ws, size_t ws_size,
                              hipStream_t stream) {
    const float* x      = (const float*)d_in[0];
    const float* W_attn = (const float*)d_in[1];
    const float* b_attn = (const float*)d_in[2];
    const float* W_proj = (const float*)d_in[3];
    const float* b_proj = (const float*)d_in[4];
    float* out = (float*)d_out;

    char* ws = (char*)d_ws;
    bf16* xh  = (bf16*)ws;  ws += (size_t)BT_ * D_ * 2;
    bf16* WaT = (bf16*)ws;  ws += (size_t)3 * D_ * D_ * 2;
    bf16* WpT = (bf16*)ws;  ws += (size_t)D_ * D_ * 2;
    bf16* Qb  = (bf16*)ws;  ws += (size_t)BH_ * T_ * HD_ * 2;
    bf16* Kb  = (bf16*)ws;  ws += (size_t)BH_ * T_ * HD_ * 2;
    bf16* Vb  = (bf16*)ws;  ws += (size_t)BH_ * T_ * HD_ * 2;
    bf16* ctx = (bf16*)ws;  ws += (size_t)BT_ * D_ * 2;

    cast_kernel<<<(BT_ * D_ / 4 + 255) / 256, 256, 0, stream>>>(x, xh, BT_ * D_ / 4);
    transpose_cast<<<dim3(3 * D_ / 32, D_ / 32), dim3(32, 8), 0, stream>>>(W_attn, WaT, D_, 3 * D_);
    transpose_cast<<<dim3(D_ / 32, D_ / 32), dim3(32, 8), 0, stream>>>(W_proj, WpT, D_, D_);

    // QKV: M=8192, N=3072 -> 32*12 = 384 blocks (384 % 8 == 0)
    gemm256<0><<<384, 512, 131072, stream>>>(xh, WaT, b_attn, Qb, Kb, Vb, nullptr);

    attn_kernel<<<dim3(BH_, 16), 256, 0, stream>>>(Qb, Kb, Vb, ctx);

    // proj: M=8192, N=1024 -> 32*4 = 128 blocks (128 % 8 == 0)
    gemm256<1><<<128, 512, 131072, stream>>>(ctx, WpT, b_proj, nullptr, nullptr, nullptr, out);
}

// Round 6
// 192.939 us; speedup vs baseline: 1.2216x; 1.2216x over previous
//
#include <hip/hip_runtime.h>
#include <hip/hip_bf16.h>

using bf16 = __hip_bfloat16;
typedef __attribute__((ext_vector_type(8))) __bf16 bf16x8;
typedef __attribute__((ext_vector_type(4))) float f32x4;

#define B_   4
#define T_   2048
#define D_   1024
#define H_   16
#define HD_  64
#define BH_  (B_ * H_)
#define BT_  (B_ * T_)

// async global->LDS DMA, 16B per lane; LDS dest is wave-uniform base + lane*16
__device__ __forceinline__ void gld_lds16(const void* g, void* l) {
    __builtin_amdgcn_global_load_lds(
        (const __attribute__((address_space(1))) unsigned int*)g,
        (__attribute__((address_space(3))) unsigned int*)l,
        16, 0, 0);
}

// ---------------------------------------------------------------- cast fp32 -> bf16
__global__ void cast_kernel(const float* __restrict__ in, bf16* __restrict__ out, int n4) {
    int i = blockIdx.x * 256 + threadIdx.x;
    if (i >= n4) return;
    float4 v = reinterpret_cast<const float4*>(in)[i];
    union { bf16 h[4]; uint2 u; } tmp;
    tmp.h[0] = __float2bfloat16(v.x);
    tmp.h[1] = __float2bfloat16(v.y);
    tmp.h[2] = __float2bfloat16(v.z);
    tmp.h[3] = __float2bfloat16(v.w);
    reinterpret_cast<uint2*>(out)[i] = tmp.u;
}

// ---------------------------------------------------------------- W[K][N] fp32 -> Wt[N][K] bf16
__global__ void transpose_cast(const float* __restrict__ W, bf16* __restrict__ Wt,
                               int K, int N) {
    __shared__ float tile[32][33];
    int nb = blockIdx.x * 32, kb = blockIdx.y * 32;
    int tx = threadIdx.x, ty = threadIdx.y;   // 32 x 8
    #pragma unroll
    for (int i = 0; i < 32; i += 8)
        tile[ty + i][tx] = W[(size_t)(kb + ty + i) * N + nb + tx];
    __syncthreads();
    #pragma unroll
    for (int i = 0; i < 32; i += 8)
        Wt[(size_t)(nb + ty + i) * K + kb + tx] = __float2bfloat16(tile[tx][ty + i]);
}

// ---------------------------------------------------------------- GEMM  C = A @ Bt^T (+bias)
// 128x128 tile, BK=32, double-buffered DMA staging (issue-early, 1 barrier/iter),
// XOR-swizzled LDS (chunk ^= (row>>1)&3; verified 0-conflict machinery from R5).
// MODE 0: QKV scatter epilogue (Q*0.125, K, V^T). MODE 1: fp32 out + bias.
template <int MODE>
__global__ __launch_bounds__(256)
void gemm_bt(const bf16* __restrict__ A, const bf16* __restrict__ Bt,
             const float* __restrict__ bias,
             bf16* __restrict__ Qo, bf16* __restrict__ Ko, bf16* __restrict__ Vo,
             float* __restrict__ Fo, int K) {
    const int bm = blockIdx.x * 128;
    const int bn = blockIdx.y * 128;
    const int tid  = threadIdx.x;
    const int wid  = tid >> 6;
    const int lane = tid & 63;
    const int wr = (wid >> 1) * 64;
    const int wc = (wid & 1) * 64;
    const int ln_g = lane >> 4;    // 0..3
    const int ln_c = lane & 15;    // 0..15

    // [buf][A=0/B=1][row 128][col 32] bf16, linear (DMA dest), 32 KiB total
    __shared__ bf16 sm[2][2][128][32];

    f32x4 acc[4][4] = {};

    // staging mapping: 4 waves x 2 calls x 16 rows = 128 rows; lane -> row l>>2, chunk l&3
    const int g_row0 = wid * 32 + (lane >> 2);                 // call 0 row
    const int g_chk  = ((lane & 3) ^ ((lane >> 3) & 3)) * 8;   // pre-swizzled elem offset
    const int l_row0 = wid * 32;                               // wave-uniform LDS row base

    // read-side swizzle folds to a per-thread constant byte offset (0..63)
    const int colx = (ln_g * 16) ^ (((ln_c >> 1) & 3) << 4);

#define STAGE(BUF_, K0_) {                                                              \
    gld_lds16(&A [(size_t)(bm + g_row0)      * K + (K0_) + g_chk], &sm[BUF_][0][l_row0][0]);      \
    gld_lds16(&A [(size_t)(bm + g_row0 + 16) * K + (K0_) + g_chk], &sm[BUF_][0][l_row0 + 16][0]); \
    gld_lds16(&Bt[(size_t)(bn + g_row0)      * K + (K0_) + g_chk], &sm[BUF_][1][l_row0][0]);      \
    gld_lds16(&Bt[(size_t)(bn + g_row0 + 16) * K + (K0_) + g_chk], &sm[BUF_][1][l_row0 + 16][0]); }

#define COMPUTE(BUF_) {                                                                  \
    bf16x8 af[4], bfr[4];                                                                \
    _Pragma("unroll")                                                                    \
    for (int m = 0; m < 4; ++m)                                                          \
        af[m] = *reinterpret_cast<const bf16x8*>(                                        \
            (const char*)&sm[BUF_][0][wr + m * 16 + ln_c][0] + colx);                    \
    _Pragma("unroll")                                                                    \
    for (int n = 0; n < 4; ++n)                                                          \
        bfr[n] = *reinterpret_cast<const bf16x8*>(                                       \
            (const char*)&sm[BUF_][1][wc + n * 16 + ln_c][0] + colx);                    \
    _Pragma("unroll")                                                                    \
    for (int m = 0; m < 4; ++m)                                                          \
        _Pragma("unroll")                                                                \
        for (int n = 0; n < 4; ++n)                                                      \
            acc[m][n] = __builtin_amdgcn_mfma_f32_16x16x32_bf16(af[m], bfr[n],           \
                                                                 acc[m][n], 0, 0, 0); }

    const int NT = K >> 5;             // 32-wide K tiles (K=1024 -> 32)
    STAGE(0, 0);
    __syncthreads();                   // drains vmcnt(0): buf0 ready

    for (int t = 0; t < NT - 2; t += 2) {
        STAGE(1, (t + 1) * 32);        // issue-early: DMA flies under compute
        COMPUTE(0);
        __syncthreads();               // drains vmcnt: buf1 ready; buf0 reads done
        STAGE(0, (t + 2) * 32);
        COMPUTE(1);
        __syncthreads();
    }
    STAGE(1, (NT - 1) * 32);
    COMPUTE(0);
    __syncthreads();
    COMPUTE(1);

#undef STAGE
#undef COMPUTE

    // epilogue
    #pragma unroll
    for (int m = 0; m < 4; ++m) {
        #pragma unroll
        for (int n = 0; n < 4; ++n) {
            const int col = bn + wc + n * 16 + ln_c;
            const float bcol = bias[col];
            #pragma unroll
            for (int j = 0; j < 4; ++j) {
                const int row = bm + wr + m * 16 + ln_g * 4 + j;
                float v = acc[m][n][j] + bcol;
                if (MODE == 0) {
                    const int part = col >> 10;       // 0=q 1=k 2=v
                    const int cc = col & 1023;
                    const int h = cc >> 6, d = cc & 63;
                    const int b = row >> 11, t = row & 2047;
                    const int bh = b * H_ + h;
                    if (part == 0)
                        Qo[((size_t)bh * T_ + t) * HD_ + d] = __float2bfloat16(v * 0.125f);
                    else if (part == 1)
                        Ko[((size_t)bh * T_ + t) * HD_ + d] = __float2bfloat16(v);
                    else
                        Vo[((size_t)bh * HD_ + d) * T_ + t] = __float2bfloat16(v);
                } else {
                    Fo[(size_t)row * D_ + col] = v;
                }
            }
        }
    }
}

// ---------------------------------------------------------------- causal flash attention v2
// Swapped-operand: S^T = mfma(K, Q) so q = lane&15 (running m/l are lane-scalars);
// O^T = mfma(V^T, P^T) so the alpha rescale is also lane-local.
// Q,K: [bh][t][64] bf16 (Q pre-scaled by 1/8). Vt: [bh][64][t] bf16.
// Grid: (BH, 16 pairs). Block processes q-tiles {p, 31-p}: exactly 33 kv-iters each.
__global__ __launch_bounds__(256)
void attn_kernel(const bf16* __restrict__ Q, const bf16* __restrict__ K,
                 const bf16* __restrict__ Vt, bf16* __restrict__ ctx) {
    const int bh = blockIdx.x;       // 0..63
    const int pr = blockIdx.y;       // 0..15
    const int tid  = threadIdx.x;
    const int wave = tid >> 6;
    const int lane = tid & 63;
    const int ln_g = lane >> 4;      // 0..3
    const int ln_c = lane & 15;      // 0..15

    const bf16* Qp = Q  + (size_t)bh * T_ * HD_;
    const bf16* Kp = K  + (size_t)bh * T_ * HD_;
    const bf16* Vp = Vt + (size_t)bh * HD_ * T_;

    __shared__ bf16 Ks[64][72];
    __shared__ bf16 Vs[64][72];
    __shared__ bf16 Ps[4][16][72];

    const int srow = tid >> 3;       // 0..31
    const int sc8  = (tid & 7) * 8;  // 0..56

    const int b = bh >> 4, h = bh & 15;

    #pragma unroll
    for (int s = 0; s < 2; ++s) {
        const int qt = (s == 0) ? pr : (31 - pr);
        const int qbase = qt * 64;
        const int qglob = qbase + wave * 16 + ln_c;    // this lane's q row

        const bf16x8 qf0 = *reinterpret_cast<const bf16x8*>(&Qp[(size_t)qglob * HD_ + ln_g * 8]);
        const bf16x8 qf1 = *reinterpret_cast<const bf16x8*>(&Qp[(size_t)qglob * HD_ + 32 + ln_g * 8]);

        f32x4 o[4] = {};
        float m = -INFINITY, l = 0.f;

        const int nk = qt + 1;          // 64-wide kv tiles

        int4 kr0, kr1, vr0, vr1;
        {
            kr0 = *reinterpret_cast<const int4*>(&Kp[(size_t)srow * HD_ + sc8]);
            kr1 = *reinterpret_cast<const int4*>(&Kp[(size_t)(srow + 32) * HD_ + sc8]);
            vr0 = *reinterpret_cast<const int4*>(&Vp[(size_t)srow * T_ + sc8]);
            vr1 = *reinterpret_cast<const int4*>(&Vp[(size_t)(srow + 32) * T_ + sc8]);
        }
        __syncthreads();
        *reinterpret_cast<int4*>(&Ks[srow][sc8])      = kr0;
        *reinterpret_cast<int4*>(&Ks[srow + 32][sc8]) = kr1;
        *reinterpret_cast<int4*>(&Vs[srow][sc8])      = vr0;
        *reinterpret_cast<int4*>(&Vs[srow + 32][sc8]) = vr1;
        __syncthreads();

        for (int it = 0; it < nk; ++it) {
            const int kb = it * 64;
            const bool notlast = (it + 1 < nk);
            if (notlast) {
                const int kn = kb + 64;
                kr0 = *reinterpret_cast<const int4*>(&Kp[(size_t)(kn + srow) * HD_ + sc8]);
                kr1 = *reinterpret_cast<const int4*>(&Kp[(size_t)(kn + srow + 32) * HD_ + sc8]);
                vr0 = *reinterpret_cast<const int4*>(&Vp[(size_t)srow * T_ + kn + sc8]);
                vr1 = *reinterpret_cast<const int4*>(&Vp[(size_t)(srow + 32) * T_ + kn + sc8]);
            }

            f32x4 st[4];
            #pragma unroll
            for (int kk = 0; kk < 4; ++kk) {
                bf16x8 kfa = *reinterpret_cast<const bf16x8*>(&Ks[kk * 16 + ln_c][ln_g * 8]);
                bf16x8 kfb = *reinterpret_cast<const bf16x8*>(&Ks[kk * 16 + ln_c][32 + ln_g * 8]);
                f32x4 z = {0.f, 0.f, 0.f, 0.f};
                z = __builtin_amdgcn_mfma_f32_16x16x32_bf16(kfa, qf0, z, 0, 0, 0);
                z = __builtin_amdgcn_mfma_f32_16x16x32_bf16(kfb, qf1, z, 0, 0, 0);
                st[kk] = z;
            }

            if (!notlast) {
                #pragma unroll
                for (int kk = 0; kk < 4; ++kk)
                    #pragma unroll
                    for (int j = 0; j < 4; ++j)
                        if (kb + kk * 16 + ln_g * 4 + j > qglob) st[kk][j] = -INFINITY;
            }

            float mx = -INFINITY;
            #pragma unroll
            for (int kk = 0; kk < 4; ++kk)
                #pragma unroll
                for (int j = 0; j < 4; ++j)
                    mx = fmaxf(mx, st[kk][j]);
            mx = fmaxf(mx, __shfl_xor(mx, 16));
            mx = fmaxf(mx, __shfl_xor(mx, 32));
            const float mnew = fmaxf(m, mx);
            const float alpha = __expf(m - mnew);
            float rs = 0.f;
            #pragma unroll
            for (int kk = 0; kk < 4; ++kk) {
                union { bf16 hh[4]; uint2 u; } pk;
                #pragma unroll
                for (int j = 0; j < 4; ++j) {
                    float p = __expf(st[kk][j] - mnew);
                    rs += p;
                    pk.hh[j] = __float2bfloat16(p);
                }
                *reinterpret_cast<uint2*>(&Ps[wave][ln_c][kk * 16 + ln_g * 4]) = pk.u;
            }
            rs += __shfl_xor(rs, 16);
            rs += __shfl_xor(rs, 32);
            l = l * alpha + rs;
            m = mnew;
            #pragma unroll
            for (int dt = 0; dt < 4; ++dt)
                #pragma unroll
                for (int j = 0; j < 4; ++j)
                    o[dt][j] *= alpha;

            const bf16x8 pf0 = *reinterpret_cast<const bf16x8*>(&Ps[wave][ln_c][ln_g * 8]);
            const bf16x8 pf1 = *reinterpret_cast<const bf16x8*>(&Ps[wave][ln_c][32 + ln_g * 8]);
            #pragma unroll
            for (int dt = 0; dt < 4; ++dt) {
                bf16x8 vfa = *reinterpret_cast<const bf16x8*>(&Vs[dt * 16 + ln_c][ln_g * 8]);
                bf16x8 vfb = *reinterpret_cast<const bf16x8*>(&Vs[dt * 16 + ln_c][32 + ln_g * 8]);
                o[dt] = __builtin_amdgcn_mfma_f32_16x16x32_bf16(vfa, pf0, o[dt], 0, 0, 0);
                o[dt] = __builtin_amdgcn_mfma_f32_16x16x32_bf16(vfb, pf1, o[dt], 0, 0, 0);
            }

            if (notlast) {
                __syncthreads();
                *reinterpret_cast<int4*>(&Ks[srow][sc8])      = kr0;
                *reinterpret_cast<int4*>(&Ks[srow + 32][sc8]) = kr1;
                *reinterpret_cast<int4*>(&Vs[srow][sc8])      = vr0;
                *reinterpret_cast<int4*>(&Vs[srow + 32][sc8]) = vr1;
                __syncthreads();
            }
        }

        const float inv = 1.0f / l;
        bf16* dst = ctx + ((size_t)(b * T_ + qglob)) * D_ + h * HD_;
        #pragma unroll
        for (int dt = 0; dt < 4; ++dt) {
            union { bf16 hh[4]; uint2 u; } ok;
            #pragma unroll
            for (int j = 0; j < 4; ++j)
                ok.hh[j] = __float2bfloat16(o[dt][j] * inv);
            *reinterpret_cast<uint2*>(&dst[dt * 16 + ln_g * 4]) = ok.u;
        }
    }
}

// ---------------------------------------------------------------- launch
extern "C" void kernel_launch(void* const* d_in, const int* in_sizes, int n_in,
                              void* d_out, int out_size, void* d_ws, size_t ws_size,
                              hipStream_t stream) {
    const float* x      = (const float*)d_in[0];
    const float* W_attn = (const float*)d_in[1];
    const float* b_attn = (const float*)d_in[2];
    const float* W_proj = (const float*)d_in[3];
    const float* b_proj = (const float*)d_in[4];
    float* out = (float*)d_out;

    char* ws = (char*)d_ws;
    bf16* xh  = (bf16*)ws;  ws += (size_t)BT_ * D_ * 2;
    bf16* WaT = (bf16*)ws;  ws += (size_t)3 * D_ * D_ * 2;
    bf16* WpT = (bf16*)ws;  ws += (size_t)D_ * D_ * 2;
    bf16* Qb  = (bf16*)ws;  ws += (size_t)BH_ * T_ * HD_ * 2;
    bf16* Kb  = (bf16*)ws;  ws += (size_t)BH_ * T_ * HD_ * 2;
    bf16* Vb  = (bf16*)ws;  ws += (size_t)BH_ * T_ * HD_ * 2;
    bf16* ctx = (bf16*)ws;  ws += (size_t)BT_ * D_ * 2;

    cast_kernel<<<(BT_ * D_ / 4 + 255) / 256, 256, 0, stream>>>(x, xh, BT_ * D_ / 4);
    transpose_cast<<<dim3(3 * D_ / 32, D_ / 32), dim3(32, 8), 0, stream>>>(W_attn, WaT, D_, 3 * D_);
    transpose_cast<<<dim3(D_ / 32, D_ / 32), dim3(32, 8), 0, stream>>>(W_proj, WpT, D_, D_);

    gemm_bt<0><<<dim3(BT_ / 128, 3 * D_ / 128), 256, 0, stream>>>(
        xh, WaT, b_attn, Qb, Kb, Vb, nullptr, D_);

    attn_kernel<<<dim3(BH_, 16), 256, 0, stream>>>(Qb, Kb, Vb, ctx);

    gemm_bt<1><<<dim3(BT_ / 128, D_ / 128), 256, 0, stream>>>(
        ctx, WpT, b_proj, nullptr, nullptr, nullptr, out, D_);
}